// Round 1
// baseline (265.911 us; speedup 1.0000x reference)
//
#include <hip/hip_runtime.h>
#include <hip/hip_bf16.h>
#include <math.h>

// ---------------------------------------------------------------------------
// MultiHeadAttention: x[4,2048,1024] -> causal MHA (16 heads, d=64) -> out proj
// bf16 MFMA everywhere.
// R12: QKV GEMM rebuilt as 256x256/BK=64 8-wave deep-pipelined kernel
// (counted vmcnt(8), raw s_barrier, setprio MFMA clusters, XCD swizzle) --
// the T1+T3+T4+T5 stack from the verified 256^2 ladder. 128 KiB LDS dbuf.
// Staging keeps the R11-verified XOR swizzle (0 bank conflicts).
// attn / prep / out-proj GEMM unchanged this round.
// ---------------------------------------------------------------------------

typedef __bf16  bf16x8  __attribute__((ext_vector_type(8)));
typedef __bf16  bf16x2  __attribute__((ext_vector_type(2)));
typedef float   floatx4 __attribute__((ext_vector_type(4)));
typedef short   shortx4 __attribute__((ext_vector_type(4)));

#if __has_builtin(__builtin_amdgcn_mfma_f32_16x16x16bf16_1k)
#define HAVE_MFMA16 1
#endif

__device__ __forceinline__ unsigned short f2bf(float f) {
    __hip_bfloat16 h = __float2bfloat16(f);
    return *reinterpret_cast<unsigned short*>(&h);
}

// pack two f32 -> 2xbf16 in one dword (HW packed cvt when available)
__device__ __forceinline__ unsigned int pkbf(float a, float b) {
#if __has_builtin(__builtin_amdgcn_cvt_pk_bf16_f32)
    bf16x2 t = __builtin_amdgcn_cvt_pk_bf16_f32(a, b);
    return __builtin_bit_cast(unsigned int, t);
#else
    return (unsigned int)f2bf(a) | ((unsigned int)f2bf(b) << 16);
#endif
}
__device__ __forceinline__ ushort4 pk4(float a, float b, float c, float d) {
    union { ushort4 u; unsigned int w[2]; } u;
    u.w[0] = pkbf(a, b);
    u.w[1] = pkbf(c, d);
    return u.u;
}

// async global->LDS, 16 B per lane; LDS dest = wave-uniform base + lane*16
__device__ __forceinline__ void gll16(const unsigned short* g, unsigned short* l) {
    __builtin_amdgcn_global_load_lds(
        (const __attribute__((address_space(1))) unsigned int*)g,
        (__attribute__((address_space(3))) unsigned int*)l, 16, 0, 0);
}

// --------------------------------------------- fused convert x + transpose W
__global__ void prep(const float* __restrict__ x, unsigned short* __restrict__ xb,
                     const float* __restrict__ Wq, const float* __restrict__ Wk,
                     const float* __restrict__ Wv, const float* __restrict__ Wo,
                     unsigned short* __restrict__ WT, unsigned short* __restrict__ WoT) {
    __shared__ float tile[32][33];
    int bid = blockIdx.x, tid = threadIdx.x;
    if (bid < 8192) {
        int i = (bid * 256 + tid) * 4;
        float4 v = *(const float4*)(x + i);
        *(ushort4*)(xb + i) = pk4(v.x, v.y, v.z, v.w);
        return;
    }
    int id = bid - 8192;
    int mat = id >> 10, rem = id & 1023;
    const float* src = (mat == 0) ? Wq : (mat == 1) ? Wk : (mat == 2) ? Wv : Wo;
    unsigned short* dst = (mat < 3) ? WT : WoT;
    int nbase = (mat < 3) ? mat * 1024 : 0;
    int kt = (rem & 31) * 32, nt = (rem >> 5) * 32;
    int tx = tid & 31, ty = tid >> 5;  // 32 x 8
    for (int j = 0; j < 32; j += 8)
        tile[ty + j][tx] = src[(kt + ty + j) * 1024 + nt + tx];
    __syncthreads();
    for (int j = 0; j < 32; j += 8) {
        int n = nt + ty + j;
        dst[(nbase + n) * 1024 + kt + tx] = f2bf(tile[tx][ty + j]);
    }
}

// ---------------------------------------------------------------- QKV GEMM
// C[8192,3072] = A[8192,1024] @ B^T (B stored [3072][1024]).
// 256x256 tile, BK=64, 512 threads / 8 waves (2M x 4N), per-wave 128x64.
// Deep pipeline: dbuf LDS; tile t+1 staged via gll16 right after tile t-1's
// read-done barrier; counted s_waitcnt vmcnt(8) (t+2's loads stay in flight
// across barriers); raw s_barrier (no compiler vmcnt(0) drain); setprio(1)
// around each 16-MFMA quadrant cluster; plain inter-phase barriers for wave
// role-split. XOR-swizzled staging (0 bank conflicts). XCD-bijective swizzle.
#define FENCE asm volatile("" ::: "memory")

#define LDA_FRAG(dst, MQ)                                              \
    _Pragma("unroll") for (int ks_ = 0; ks_ < 2; ++ks_)                \
    _Pragma("unroll") for (int i_ = 0; i_ < 4; ++i_) {                 \
        int row_ = wm * 128 + (MQ) * 64 + i_ * 16 + lm;                \
        int pu_ = ((ks_ * 4 + quad) ^ (lm & 7)) * 8;                   \
        dst[ks_][i_] = *(const bf16x8*)&Ac[row_ * 64 + pu_];           \
    }

#define LDB_FRAG(dst, NQ)                                              \
    _Pragma("unroll") for (int ks_ = 0; ks_ < 2; ++ks_)                \
    _Pragma("unroll") for (int j_ = 0; j_ < 2; ++j_) {                 \
        int row_ = wn * 64 + (NQ) * 32 + j_ * 16 + lm;                 \
        int pu_ = ((ks_ * 4 + quad) ^ (lm & 7)) * 8;                   \
        dst[ks_][j_] = *(const bf16x8*)&Bc[row_ * 64 + pu_];           \
    }

#define MMA_Q(afr, bfr, MQ, NQ)                                                            \
    __builtin_amdgcn_s_setprio(1);                                                         \
    if (sw) {                                                                              \
        _Pragma("unroll") for (int i_ = 0; i_ < 4; ++i_)                                   \
        _Pragma("unroll") for (int j_ = 0; j_ < 2; ++j_) {                                 \
            floatx4& c_ = acc[(MQ) * 4 + i_][(NQ) * 2 + j_];                               \
            c_ = __builtin_amdgcn_mfma_f32_16x16x32_bf16(bfr[0][j_], afr[0][i_], c_, 0, 0, 0); \
            c_ = __builtin_amdgcn_mfma_f32_16x16x32_bf16(bfr[1][j_], afr[1][i_], c_, 0, 0, 0); \
        }                                                                                  \
    } else {                                                                               \
        _Pragma("unroll") for (int i_ = 0; i_ < 4; ++i_)                                   \
        _Pragma("unroll") for (int j_ = 0; j_ < 2; ++j_) {                                 \
            floatx4& c_ = acc[(MQ) * 4 + i_][(NQ) * 2 + j_];                               \
            c_ = __builtin_amdgcn_mfma_f32_16x16x32_bf16(afr[0][i_], bfr[0][j_], c_, 0, 0, 0); \
            c_ = __builtin_amdgcn_mfma_f32_16x16x32_bf16(afr[1][i_], bfr[1][j_], c_, 0, 0, 0); \
        }                                                                                  \
    }                                                                                      \
    __builtin_amdgcn_s_setprio(0);

__global__ __launch_bounds__(512, 2) void gemm_qkv(const unsigned short* __restrict__ A,
                                                   const unsigned short* __restrict__ B,
                                                   unsigned short* __restrict__ Qo,
                                                   unsigned short* __restrict__ Ko,
                                                   unsigned short* __restrict__ Vo) {
    __shared__ __align__(16) unsigned short As[2][256 * 64];
    __shared__ __align__(16) unsigned short Bs[2][256 * 64];

    int tid = threadIdx.x;
    int lane = tid & 63, w = tid >> 6;       // 8 waves
    int wm = w >> 2, wn = w & 3;             // 2 x 4 wave grid, wave tile 128x64
    int lm = lane & 15, quad = lane >> 4;

    // XCD-bijective swizzle: 384 blocks, 48/XCD, bn-fastest within the chunk
    // (each XCD keeps 4 A-panels = 2 MB L2-resident).
    int bid = blockIdx.x;
    int swz = (bid & 7) * 48 + (bid >> 3);
    int bm = swz / 12, bn = swz % 12;
    int m0 = bm * 256, n0 = bn * 256;
    bool sw = (n0 < 2048);                   // C^T orientation for Q/K columns

    const unsigned short* Ag = A + (size_t)m0 * 1024;
    const unsigned short* Bg = B + (size_t)n0 * 1024;

    // stage one full 256x64 K-tile of A and B (8 gll16/thread, XOR swizzle)
    auto STAGE = [&](int bufi, int kb) {
#pragma unroll
        for (int p = 0; p < 4; ++p) {
            int id = p * 512 + tid;
            int row = id >> 3;                          // 0..255
            int cbs = ((id & 7) ^ (row & 7)) * 8;       // XOR-swizzled src unit
            int lofs = (p * 512 + w * 64) * 8;          // wave-uniform; HW adds lane*16B
            gll16(&Ag[row * 1024 + kb + cbs], &As[bufi][lofs]);
            gll16(&Bg[row * 1024 + kb + cbs], &Bs[bufi][lofs]);
        }
    };

    floatx4 acc[8][4] = {};

    // prologue: tiles 0,1 in flight; wait only tile 0 (counted vmcnt)
    STAGE(0, 0);
    STAGE(1, 64);
    asm volatile("s_waitcnt vmcnt(8)" ::: "memory");
    FENCE; __builtin_amdgcn_s_barrier(); FENCE;

#pragma unroll 1
    for (int t = 0; t < 16; ++t) {
        const unsigned short* Ac = As[t & 1];
        const unsigned short* Bc = Bs[t & 1];
        bf16x8 a0[2][4], a1[2][4], b0[2][2], b1[2][2];

        // phase 1: quadrant (0,0)
        LDA_FRAG(a0, 0);
        LDB_FRAG(b0, 0);
        MMA_Q(a0, b0, 0, 0);
        __builtin_amdgcn_s_barrier();
        // phase 2: quadrant (0,1)
        LDB_FRAG(b1, 1);
        MMA_Q(a0, b1, 0, 1);
        __builtin_amdgcn_s_barrier();
        // phase 3: quadrant (1,1)
        LDA_FRAG(a1, 1);
        MMA_Q(a1, b1, 1, 1);
        __builtin_amdgcn_s_barrier();
        // phase 4: quadrant (1,0) -- b0 still live
        MMA_Q(a1, b0, 1, 0);

        // b1: every wave done READING buf[t&1] -> safe to restage it
        FENCE; __builtin_amdgcn_s_barrier(); FENCE;
        if (t + 2 < 16) STAGE(t & 1, (t + 2) * 64);
        if (t + 1 < 16) {
            // wait own tile-(t+1) loads; tile-(t+2) loads stay in flight
            if (t + 2 < 16) { asm volatile("s_waitcnt vmcnt(8)" ::: "memory"); }
            else            { asm volatile("s_waitcnt vmcnt(0)" ::: "memory"); }
            // b2: joins all waves -> buf[(t+1)&1] published
            FENCE; __builtin_amdgcn_s_barrier(); FENCE;
        }
    }

    if (sw) {
        // C^T layout: lane owns seq s (col=lm) and 4 consecutive out-cols.
        bool isQ = (n0 < 1024);
        unsigned short* dst = isQ ? Qo : Ko;
        float qs = isQ ? 0.1803368801f : 1.0f;  // 1/8 * log2(e)
#pragma unroll
        for (int mi = 0; mi < 8; ++mi) {
            int s = m0 + wm * 128 + mi * 16 + lm;
            int bb = s >> 11, sl = s & 2047;
#pragma unroll
            for (int ni = 0; ni < 4; ++ni) {
                int gcol0 = n0 + wn * 64 + ni * 16 + quad * 4;
                int h = (gcol0 & 1023) >> 6, d0 = gcol0 & 63;
                *(ushort4*)&dst[(((size_t)(bb * 16 + h) * 2048) + sl) * 64 + d0] =
                    pk4(acc[mi][ni][0] * qs, acc[mi][ni][1] * qs,
                        acc[mi][ni][2] * qs, acc[mi][ni][3] * qs);
            }
        }
    } else {
        // V columns, normal layout: packed along seq for V^T [bh][d][2048].
#pragma unroll
        for (int mi = 0; mi < 8; ++mi) {
            int grow0 = m0 + wm * 128 + mi * 16 + quad * 4;
            int bb = grow0 >> 11, sl = grow0 & 2047;
#pragma unroll
            for (int ni = 0; ni < 4; ++ni) {
                int gcol = n0 + wn * 64 + ni * 16 + lm;
                int hn = gcol & 1023;
                int h = hn >> 6, d = hn & 63;
                *(ushort4*)&Vo[((size_t)(bb * 16 + h) * 64 + d) * 2048 + sl] =
                    pk4(acc[mi][ni][0], acc[mi][ni][1], acc[mi][ni][2], acc[mi][ni][3]);
            }
        }
    }
}

// ---------------------------------------------------------------- GEMM B^T
// (out-proj only now) C[M,N] = A[M,1024] @ B^T. 128x128 tile, BK=64.
// Single-buffer gll16 staging with XOR swizzle (0 bank conflicts).
template <int EPI>
__global__ __launch_bounds__(256) void gemm_bt(const unsigned short* __restrict__ A,
                                               const unsigned short* __restrict__ B,
                                               unsigned short* __restrict__ Qo,
                                               unsigned short* __restrict__ Ko,
                                               unsigned short* __restrict__ Vo,
                                               const float* __restrict__ bias,
                                               float* __restrict__ Out) {
    __shared__ __align__(16) unsigned short As[128 * 64];
    __shared__ __align__(16) unsigned short Bs[128 * 64];

    int tid = threadIdx.x;
    int lane = tid & 63, w = tid >> 6;
    int wm = w >> 1, wn = w & 1;
    int lm = lane & 15, quad = lane >> 4;
    int m0 = blockIdx.x * 128, n0 = blockIdx.y * 128;
    bool sw = (EPI == 1) || (n0 < 2048);  // block-uniform orientation

    floatx4 acc[4][4] = {};

    for (int kb = 0; kb < 1024; kb += 64) {
        __syncthreads();
        for (int p = 0; p < 4; ++p) {
            int id = p * 256 + tid;
            int row = id >> 3;
            int cbs = ((id & 7) ^ (row & 7)) * 8;  // XOR-swizzled source unit
            int lbase = (p * 256 + w * 64) * 8;    // wave-uniform; HW adds lane*16B
            gll16(&A[(m0 + row) * 1024 + kb + cbs], &As[lbase]);
            gll16(&B[(n0 + row) * 1024 + kb + cbs], &Bs[lbase]);
        }
        __syncthreads();
        bf16x8 af[2][4], bf[2][4];
        for (int ks = 0; ks < 2; ++ks)
            for (int i = 0; i < 4; ++i) {
                int pu = (((ks * 4 + quad) ^ (lm & 7))) * 8;  // swizzled unit
                af[ks][i] = *(const bf16x8*)&As[(wm * 64 + i * 16 + lm) * 64 + pu];
                bf[ks][i] = *(const bf16x8*)&Bs[(wn * 64 + i * 16 + lm) * 64 + pu];
            }
        if (sw) {
            for (int mi = 0; mi < 4; ++mi)
                for (int ni = 0; ni < 4; ++ni) {
                    acc[mi][ni] = __builtin_amdgcn_mfma_f32_16x16x32_bf16(bf[0][ni], af[0][mi], acc[mi][ni], 0, 0, 0);
                    acc[mi][ni] = __builtin_amdgcn_mfma_f32_16x16x32_bf16(bf[1][ni], af[1][mi], acc[mi][ni], 0, 0, 0);
                }
        } else {
            for (int mi = 0; mi < 4; ++mi)
                for (int ni = 0; ni < 4; ++ni) {
                    acc[mi][ni] = __builtin_amdgcn_mfma_f32_16x16x32_bf16(af[0][mi], bf[0][ni], acc[mi][ni], 0, 0, 0);
                    acc[mi][ni] = __builtin_amdgcn_mfma_f32_16x16x32_bf16(af[1][mi], bf[1][ni], acc[mi][ni], 0, 0, 0);
                }
        }
    }

    if constexpr (EPI == 0) {
        if (sw) {
            bool isQ = (n0 < 1024);
            unsigned short* dst = isQ ? Qo : Ko;
            float qs = isQ ? 0.1803368801f : 1.0f;  // 1/8 * log2(e)
            for (int mi = 0; mi < 4; ++mi) {
                int s = m0 + wm * 64 + mi * 16 + lm;
                int bb = s >> 11, sl = s & 2047;
                for (int ni = 0; ni < 4; ++ni) {
                    int gcol0 = n0 + wn * 64 + ni * 16 + quad * 4;
                    int h = (gcol0 & 1023) >> 6, d0 = gcol0 & 63;
                    *(ushort4*)&dst[(((size_t)(bb * 16 + h) * 2048) + sl) * 64 + d0] =
                        pk4(acc[mi][ni][0] * qs, acc[mi][ni][1] * qs,
                            acc[mi][ni][2] * qs, acc[mi][ni][3] * qs);
                }
            }
        } else {
            for (int mi = 0; mi < 4; ++mi) {
                int grow0 = m0 + wm * 64 + mi * 16 + quad * 4;
                int bb = grow0 >> 11, sl = grow0 & 2047;
                for (int ni = 0; ni < 4; ++ni) {
                    int gcol = n0 + wn * 64 + ni * 16 + lm;
                    int hn = gcol & 1023;
                    int h = hn >> 6, d = hn & 63;
                    *(ushort4*)&Vo[((size_t)(bb * 16 + h) * 64 + d) * 2048 + sl] =
                        pk4(acc[mi][ni][0], acc[mi][ni][1], acc[mi][ni][2], acc[mi][ni][3]);
                }
            }
        }
    } else {
        // out-proj: C^T layout -> float4 stores + float4 bias loads
        for (int mi = 0; mi < 4; ++mi) {
            int s = m0 + wm * 64 + mi * 16 + lm;
            for (int ni = 0; ni < 4; ++ni) {
                int gcol0 = n0 + wn * 64 + ni * 16 + quad * 4;
                float4 bv = *(const float4*)&bias[gcol0];
                float4 o;
                o.x = acc[mi][ni][0] + bv.x; o.y = acc[mi][ni][1] + bv.y;
                o.z = acc[mi][ni][2] + bv.z; o.w = acc[mi][ni][3] + bv.w;
                *(float4*)&Out[(size_t)s * 1024 + gcol0] = o;
            }
        }
    }
}

// ------------------------------------------------------------- attention
// Flat grid 1024 = (qt heavy-first, 16 tiles of 128 q) x 64 bh.
// 512 thr = 8 waves x 16 q-rows. KB=64. S^T orientation: q=lm, k=quad*4+r.
// NO-MAX softmax; Q pre-scaled; lrow reduced once at the end.
__global__ __launch_bounds__(512) void attn(const unsigned short* __restrict__ Q,
                                            const unsigned short* __restrict__ K,
                                            const unsigned short* __restrict__ Vt,
                                            unsigned short* __restrict__ ctx) {
    constexpr int LKS = 72;
    __shared__ __align__(16) unsigned short Ks[2][64 * LKS];
    __shared__ __align__(16) unsigned short Vts[2][64 * LKS];

    int tid = threadIdx.x, lane = tid & 63, w = tid >> 6;   // w: 0..7
    int lm = lane & 15, quad = lane >> 4;
    int blk = blockIdx.x;
    int bh = blk & 63;
    int qt = 15 - (blk >> 6);   // LPT: heaviest q-tiles dispatch first
    int trips = 2 * qt + 2;
    int tmax = 2 * qt + (w >> 2);  // last trip this wave computes
    const unsigned short* Qg  = Q  + (size_t)bh * 2048 * 64;
    const unsigned short* Kg  = K  + (size_t)bh * 2048 * 64;
    const unsigned short* Vtg = Vt + (size_t)bh * 64 * 2048;

    int qrow = qt * 128 + w * 16 + lm;
    bf16x8 aq0 = *(const bf16x8*)&Qg[qrow * 64 + quad * 8];
    bf16x8 aq1 = *(const bf16x8*)&Qg[qrow * 64 + 32 + quad * 8];

    floatx4 O[4] = {};            // O^T: per dblk, lane holds d=quad*4+r, q=lm
    float lrow = 0.f;

    int r0 = tid >> 3, c0 = (tid & 7) * 8;  // 512 thr -> rows 0..63, 1 uint4 each

    {   // prologue: stage tile 0 into buffer 0
        uint4 k0 = *(const uint4*)&Kg[r0 * 64 + c0];
        uint4 v0 = *(const uint4*)&Vtg[r0 * 2048 + c0];
        *(uint4*)&Ks[0][r0 * LKS + c0]  = k0;
        *(uint4*)&Vts[0][r0 * LKS + c0] = v0;
    }
    __syncthreads();

    for (int t = 0; t < trips; ++t) {
        int cur = t & 1, nxt = cur ^ 1;
        bool pre = (t + 1 < trips);
        uint4 pk, pv;
        if (pre) {  // issue next tile's loads NOW; they complete under compute
            int kb2 = (t + 1) * 64;
            pk = *(const uint4*)&Kg[(kb2 + r0) * 64 + c0];
            pv = *(const uint4*)&Vtg[r0 * 2048 + kb2 + c0];
        }

        if (t <= tmax) {  // wave-uniform; barriers are outside this branch
            const unsigned short* Kc = Ks[cur];
            const unsigned short* Vc = Vts[cur];

            floatx4 s[4];
            for (int n = 0; n < 4; ++n) {
                bf16x8 a0 = *(const bf16x8*)&Kc[(n * 16 + lm) * LKS + quad * 8];
                bf16x8 a1 = *(const bf16x8*)&Kc[(n * 16 + lm) * LKS + 32 + quad * 8];
                floatx4 z = {};
                z = __builtin_amdgcn_mfma_f32_16x16x32_bf16(a0, aq0, z, 0, 0, 0);
                z = __builtin_amdgcn_mfma_f32_16x16x32_bf16(a1, aq1, z, 0, 0, 0);
                s[n] = z;
            }

            bool diag = (t == tmax);
            if (diag) {
                int qr = (w & 3) * 16 + lm;  // q - kb on this wave's diag tile
                for (int n = 0; n < 4; ++n)
                    for (int r = 0; r < 4; ++r)
                        if (n * 16 + quad * 4 + r > qr) s[n][r] = -INFINITY;
            }
            float p[4][4], rs = 0.f;
            for (int n = 0; n < 4; ++n)
                for (int r = 0; r < 4; ++r) {
                    p[n][r] = __builtin_amdgcn_exp2f(s[n][r]);
                    rs += p[n][r];
                }
            lrow += rs;

#ifdef HAVE_MFMA16
            // P^T is ALREADY the 16x16x16 B-frag (B[k=quad*4+i][n=lm]) — no LDS.
            shortx4 pb[4];
            for (int n = 0; n < 4; ++n) {
                union { shortx4 s4; unsigned int w2[2]; } u;
                u.w2[0] = pkbf(p[n][0], p[n][1]);
                u.w2[1] = pkbf(p[n][2], p[n][3]);
                pb[n] = u.s4;
            }
            for (int dblk = 0; dblk < 4; ++dblk)
                for (int n = 0; n < 4; ++n) {
                    shortx4 va = *(const shortx4*)&Vc[(dblk * 16 + lm) * LKS + n * 16 + quad * 4];
                    O[dblk] = __builtin_amdgcn_mfma_f32_16x16x16bf16_1k(va, pb[n], O[dblk], 0, 0, 0);
                }
#else
            unsigned int dw[4][2];
            for (int n = 0; n < 4; ++n) {
                dw[n][0] = pkbf(p[n][0], p[n][1]);
                dw[n][1] = pkbf(p[n][2], p[n][3]);
            }
            bool hiTile = (quad >> 1);
            for (int hh = 0; hh < 2; ++hh) {
                unsigned int bp[4];
                for (int j = 0; j < 4; ++j) {
                    int srcLane = lm + (((quad & 1) * 2 + (j >> 1)) << 4);
                    unsigned int lo = __shfl((int)dw[2 * hh][j & 1], srcLane);
                    unsigned int hi = __shfl((int)dw[2 * hh + 1][j & 1], srcLane);
                    bp[j] = hiTile ? hi : lo;
                }
                bf16x8 bfrag = *(bf16x8*)bp;
                for (int dblk = 0; dblk < 4; ++dblk) {
                    bf16x8 av = *(const bf16x8*)&Vc[(dblk * 16 + lm) * LKS + hh * 32 + quad * 8];
                    O[dblk] = __builtin_amdgcn_mfma_f32_16x16x32_bf16(av, bfrag, O[dblk], 0, 0, 0);
                }
            }
#endif
        }

        if (pre) {  // loads completed under compute; write into other buffer
            *(uint4*)&Ks[nxt][r0 * LKS + c0]  = pk;
            *(uint4*)&Vts[nxt][r0 * LKS + c0] = pv;
        }
        __syncthreads();
    }

    // reduce lrow across the 4 lane-groups holding the same q (once)
    lrow += __shfl_xor(lrow, 16);
    lrow += __shfl_xor(lrow, 32);

    int b = bh >> 4, h = bh & 15;
    int q = qt * 128 + w * 16 + lm;
    float inv = 1.0f / lrow;
    for (int dblk = 0; dblk < 4; ++dblk) {
        *(ushort4*)&ctx[((size_t)(b * 2048 + q)) * 1024 + h * 64 + dblk * 16 + quad * 4] =
            pk4(O[dblk][0] * inv, O[dblk][1] * inv, O[dblk][2] * inv, O[dblk][3] * inv);
    }
}

// ---------------------------------------------------------------- launch
extern "C" void kernel_launch(void* const* d_in, const int* in_sizes, int n_in,
                              void* d_out, int out_size, void* d_ws, size_t ws_size,
                              hipStream_t stream) {
    const float* x   = (const float*)d_in[0];
    const float* Wq  = (const float*)d_in[1];
    const float* Wk  = (const float*)d_in[2];
    const float* Wv  = (const float*)d_in[3];
    const float* Wo  = (const float*)d_in[4];
    const float* bo  = (const float*)d_in[5];
    float* out = (float*)d_out;

    char* ws = (char*)d_ws;
    unsigned short* xb  = (unsigned short*)(ws);               // 16 MB (dead after gemm_qkv)
    unsigned short* WT  = (unsigned short*)(ws + 16777216);    // 6 MB
    unsigned short* WoT = (unsigned short*)(ws + 23068672);    // 2 MB
    unsigned short* Qb  = (unsigned short*)(ws + 25165824);    // 16 MB
    unsigned short* Kb  = (unsigned short*)(ws + 41943040);    // 16 MB
    unsigned short* Vtb = (unsigned short*)(ws + 58720256);    // 16 MB (transposed)
    unsigned short* ctx = xb;                                  // alias: xb is dead

    prep<<<12288, 256, 0, stream>>>(x, xb, Wq, Wk, Wv, Wo, WT, WoT);
    gemm_qkv<<<384, 512, 0, stream>>>(xb, WT, Qb, Kb, Vtb);
    attn<<<1024, 512, 0, stream>>>(Qb, Kb, Vtb, ctx);
    gemm_bt<1><<<dim3(64, 8), 256, 0, stream>>>(ctx, WoT, nullptr, nullptr, nullptr, bo, out);
}